// Round 5
// baseline (338.499 us; speedup 1.0000x reference)
//
#include <hip/hip_runtime.h>
#include <hip/hip_fp16.h>

#define FDIM 128
#define NGRP 8   // XCD-partition groups (blockIdx & 7 round-robins XCDs)
#define LPAD 136 // LDS row stride in halfs (128 + 8): 16B-aligned rows, <=2-way banks

typedef _Float16 half8_t __attribute__((ext_vector_type(8)));
typedef _Float16 half4_t __attribute__((ext_vector_type(4)));
typedef float float4_t __attribute__((ext_vector_type(4)));

// ---------------- CSR build ----------------

__global__ void zero_kernel(int* __restrict__ p, int n) {
  int i = blockIdx.x * blockDim.x + threadIdx.x;
  if (i < n) p[i] = 0;
}

// Replicated-read, partitioned-write histogram (dst slice per XCD group).
__global__ void hist_part_kernel(const int* __restrict__ dst, int* __restrict__ deg,
                                 int E, int step) {
  int grp = blockIdx.x & (NGRP - 1);
  int nb = gridDim.x >> 3, bid = blockIdx.x >> 3;
  int lo = grp * step, hi = lo + step;
  int E4 = E >> 2;
  const int4* d4 = (const int4*)dst;
  for (int i = bid * blockDim.x + threadIdx.x; i < E4; i += nb * blockDim.x) {
    int4 d = d4[i];
    if (d.x >= lo && d.x < hi) atomicAdd(&deg[d.x], 1);
    if (d.y >= lo && d.y < hi) atomicAdd(&deg[d.y], 1);
    if (d.z >= lo && d.z < hi) atomicAdd(&deg[d.z], 1);
    if (d.w >= lo && d.w < hi) atomicAdd(&deg[d.w], 1);
  }
  for (int e = (E4 << 2) + bid * blockDim.x + threadIdx.x; e < E; e += nb * blockDim.x) {
    int d = dst[e];
    if (d >= lo && d < hi) atomicAdd(&deg[d], 1);
  }
}

__global__ void scan1_kernel(const int* __restrict__ deg, int* __restrict__ csums, int N) {
  __shared__ int sh[256];
  int t = threadIdx.x, b = blockIdx.x;
  int base = b * 1024;
  int s = 0;
#pragma unroll
  for (int i = 0; i < 4; i++) {
    int idx = base + t + 256 * i;
    if (idx < N) s += deg[idx];
  }
  sh[t] = s; __syncthreads();
  for (int off = 128; off > 0; off >>= 1) {
    if (t < off) sh[t] += sh[t + off];
    __syncthreads();
  }
  if (t == 0) csums[b] = sh[0];
}

__global__ void scan2_kernel(const int* __restrict__ csums, int* __restrict__ coffs, int nchunk) {
  __shared__ int sh[256];
  int t = threadIdx.x;
  int v = (t < nchunk) ? csums[t] : 0;
  sh[t] = v; __syncthreads();
  for (int off = 1; off < 256; off <<= 1) {
    int u = (t >= off) ? sh[t - off] : 0;
    __syncthreads();
    sh[t] += u;
    __syncthreads();
  }
  if (t < nchunk) coffs[t] = sh[t] - v;
}

__global__ void scan3_kernel(const int* __restrict__ deg, const int* __restrict__ coffs,
                             int* __restrict__ row_start, int* __restrict__ fill_pos, int N) {
  __shared__ int sh[256];
  int t = threadIdx.x, b = blockIdx.x;
  int base = b * 1024 + t * 4;
  int d0 = (base + 0 < N) ? deg[base + 0] : 0;
  int d1 = (base + 1 < N) ? deg[base + 1] : 0;
  int d2 = (base + 2 < N) ? deg[base + 2] : 0;
  int d3 = (base + 3 < N) ? deg[base + 3] : 0;
  int l1 = d0, l2 = l1 + d1, l3 = l2 + d2, tot = l3 + d3;
  sh[t] = tot; __syncthreads();
  for (int off = 1; off < 256; off <<= 1) {
    int v = (t >= off) ? sh[t - off] : 0;
    __syncthreads();
    sh[t] += v;
    __syncthreads();
  }
  int excl = sh[t] - tot + coffs[b];
  if (base + 0 < N) { row_start[base + 0] = excl;      fill_pos[base + 0] = excl; }
  if (base + 1 < N) { row_start[base + 1] = excl + l1; fill_pos[base + 1] = excl + l1; }
  if (base + 2 < N) { row_start[base + 2] = excl + l2; fill_pos[base + 2] = excl + l2; }
  if (base + 3 < N) { row_start[base + 3] = excl + l3; fill_pos[base + 3] = excl + l3; }
}

__global__ void place_part_kernel(const int* __restrict__ src, const int* __restrict__ dst,
                                  int* __restrict__ fill_pos, int* __restrict__ ssrc,
                                  int E, int step) {
  int grp = blockIdx.x & (NGRP - 1);
  int nb = gridDim.x >> 3, bid = blockIdx.x >> 3;
  int lo = grp * step, hi = lo + step;
  int E4 = E >> 2;
  const int4* d4 = (const int4*)dst;
  const int4* s4 = (const int4*)src;
  for (int i = bid * blockDim.x + threadIdx.x; i < E4; i += nb * blockDim.x) {
    int4 d = d4[i];
    bool m0 = d.x >= lo && d.x < hi, m1 = d.y >= lo && d.y < hi;
    bool m2 = d.z >= lo && d.z < hi, m3 = d.w >= lo && d.w < hi;
    if (m0 | m1 | m2 | m3) {
      int4 s = s4[i];  // only fetch src when this lane has a match
      if (m0) ssrc[atomicAdd(&fill_pos[d.x], 1)] = s.x;
      if (m1) ssrc[atomicAdd(&fill_pos[d.y], 1)] = s.y;
      if (m2) ssrc[atomicAdd(&fill_pos[d.z], 1)] = s.z;
      if (m3) ssrc[atomicAdd(&fill_pos[d.w], 1)] = s.w;
    }
  }
  for (int e = (E4 << 2) + bid * blockDim.x + threadIdx.x; e < E; e += nb * blockDim.x) {
    int d = dst[e];
    if (d >= lo && d < hi) ssrc[atomicAdd(&fill_pos[d], 1)] = src[e];
  }
}

// ---------------- convert / W pre-shuffle ----------------

__global__ void cvt_f2h_kernel(const float* __restrict__ in, _Float16* __restrict__ out, int n4) {
  int i = blockIdx.x * blockDim.x + threadIdx.x;
  if (i < n4) {
    float4 v = ((const float4*)in)[i];
    half4_t h;
    h.x = (_Float16)v.x; h.y = (_Float16)v.y; h.z = (_Float16)v.z; h.w = (_Float16)v.w;
    ((half4_t*)out)[i] = h;
  }
}

// Shuffle W1,W2 (fp32 row-major [k][n]) into per-lane MFMA B-fragment order:
//   Wf[((wave*2+ct)*4+kb)*64 + lane][j] = W[(kb*32+quad*8+j)*128 + wave*32+ct*16+m16]
__global__ void prepw2_kernel(const float* __restrict__ W1, _Float16* __restrict__ Wf1,
                              const float* __restrict__ W2, _Float16* __restrict__ Wf2) {
  int gid = blockIdx.x * blockDim.x + threadIdx.x;  // 32768
  int which = gid >> 14;
  int tid = gid & 16383;
  const float* W = which ? W2 : W1;
  _Float16* Wf = which ? Wf2 : Wf1;
  int j = tid & 7, lane = (tid >> 3) & 63, rest = tid >> 9;
  int kb = rest & 3, ct = (rest >> 2) & 1, wave = rest >> 3;
  int quad = lane >> 4, m16 = lane & 15;
  int k = kb * 32 + quad * 8 + j;
  int n = wave * 32 + ct * 16 + m16;
  Wf[tid] = (_Float16)W[k * FDIM + n];
}

// ---------------- fused layer: gather-agg (LDS) + MFMA GEMM + bias/ReLU + stats ----------
// 64 nodes per block; 4 waves each aggregate 16 nodes into LDS (fp16), then the
// block runs the 64x128 @ 128x128 MFMA tile with fused epilogue.
// C/D layout: row = quad*4 + reg, col = lane&15 (m89-verified).

__device__ inline float2 up2(unsigned u) {
  __half2 h = *(__half2*)&u;
  return __half22float2(h);
}

template <bool LAYER2>
__global__ __launch_bounds__(256) void layer_kernel(
    const unsigned* __restrict__ xu, const int* __restrict__ row_start,
    const int* __restrict__ deg, const int* __restrict__ ssrc,
    const float* __restrict__ ascale, const _Float16* __restrict__ Wf,
    const float* __restrict__ bias, const float* __restrict__ r2,
    _Float16* __restrict__ outh, float* __restrict__ ssum, float* __restrict__ ssq,
    int N) {
  __shared__ _Float16 sA[64 * LPAD];
  __shared__ float sdn[64];
  int t = threadIdx.x;
  int wave = t >> 6, lane = t & 63;
  int quad = lane >> 4, m16 = lane & 15;
  int row0 = blockIdx.x * 64;

  // B fragments early: 8 coalesced half8 loads (L2-hot), in flight during agg
  half8_t bf[2][4];
  const half8_t* wf8 = (const half8_t*)Wf;
#pragma unroll
  for (int ct = 0; ct < 2; ct++)
#pragma unroll
    for (int kb = 0; kb < 4; kb++)
      bf[ct][kb] = wf8[(size_t)(((wave * 2 + ct) * 4 + kb) * 64 + lane)];

  if (LAYER2) {
    if (t < 64) {
      int r = row0 + t;
      sdn[t] = (r < N) ? (float)(deg[r] + 1) : 0.f;
    }
  }

  // phase 1: each wave aggregates 16 node rows into LDS
  for (int i = 0; i < 16; i++) {
    int node = row0 + (wave << 4) + i;
    if (node >= N) break;
    float2 c0 = up2(xu[(size_t)node * 64 + lane]);
    float2 c1 = make_float2(0.f, 0.f), c2 = c1, c3 = c1;
    int start = row_start[node], d = deg[node];
    int k = 0;
    for (; k + 7 < d; k += 8) {
      int s0 = ssrc[start + k + 0], s1 = ssrc[start + k + 1];
      int s2 = ssrc[start + k + 2], s3 = ssrc[start + k + 3];
      int s4 = ssrc[start + k + 4], s5 = ssrc[start + k + 5];
      int s6 = ssrc[start + k + 6], s7 = ssrc[start + k + 7];
      unsigned u0 = xu[(size_t)s0 * 64 + lane], u1 = xu[(size_t)s1 * 64 + lane];
      unsigned u2 = xu[(size_t)s2 * 64 + lane], u3 = xu[(size_t)s3 * 64 + lane];
      unsigned u4 = xu[(size_t)s4 * 64 + lane], u5 = xu[(size_t)s5 * 64 + lane];
      unsigned u6 = xu[(size_t)s6 * 64 + lane], u7 = xu[(size_t)s7 * 64 + lane];
      float2 v0 = up2(u0), v1 = up2(u1), v2 = up2(u2), v3 = up2(u3);
      float2 v4 = up2(u4), v5 = up2(u5), v6 = up2(u6), v7 = up2(u7);
      c0.x += v0.x + v4.x; c0.y += v0.y + v4.y;
      c1.x += v1.x + v5.x; c1.y += v1.y + v5.y;
      c2.x += v2.x + v6.x; c2.y += v2.y + v6.y;
      c3.x += v3.x + v7.x; c3.y += v3.y + v7.y;
    }
    for (; k + 1 < d; k += 2) {
      int s0 = ssrc[start + k], s1 = ssrc[start + k + 1];
      unsigned u0 = xu[(size_t)s0 * 64 + lane], u1 = xu[(size_t)s1 * 64 + lane];
      float2 v0 = up2(u0), v1 = up2(u1);
      c0.x += v0.x; c0.y += v0.y;
      c1.x += v1.x; c1.y += v1.y;
    }
    if (k < d) {
      float2 v = up2(xu[(size_t)ssrc[start + k] * 64 + lane]);
      c0.x += v.x; c0.y += v.y;
    }
    float2 acc;
    acc.x = (c0.x + c1.x) + (c2.x + c3.x);
    acc.y = (c0.y + c1.y) + (c2.y + c3.y);
    if (LAYER2) {
      float2 av = ((const float2*)ascale)[lane];
      acc.x *= av.x; acc.y *= av.y;
    }
    __half2 r = __float22half2_rn(acc);
    *(__half2*)&sA[(size_t)((wave << 4) + i) * LPAD + 2 * lane] = r;
  }
  __syncthreads();

  // phase 2: MFMA on LDS A-tiles
  float4_t acc[4][2] = {};
#pragma unroll
  for (int rt = 0; rt < 4; rt++) {
#pragma unroll
    for (int kb = 0; kb < 4; kb++) {
      half8_t av = *(const half8_t*)&sA[(size_t)(rt * 16 + m16) * LPAD + kb * 32 + quad * 8];
      acc[rt][0] = __builtin_amdgcn_mfma_f32_16x16x32_f16(av, bf[0][kb], acc[rt][0], 0, 0, 0);
      acc[rt][1] = __builtin_amdgcn_mfma_f32_16x16x32_f16(av, bf[1][kb], acc[rt][1], 0, 0, 0);
    }
  }

  // epilogue: bias (+ (deg+1)*r2 for layer 2), ReLU, store fp16, fused BN stats
#pragma unroll
  for (int ct = 0; ct < 2; ct++) {
    int col = wave * 32 + ct * 16 + m16;
    float bv = bias[col];
    float rv = LAYER2 ? r2[col] : 0.f;
    float s = 0.f, q = 0.f;
#pragma unroll
    for (int rt = 0; rt < 4; rt++) {
#pragma unroll
      for (int r = 0; r < 4; r++) {
        int row = row0 + rt * 16 + quad * 4 + r;
        if (row < N) {
          float v = acc[rt][ct][r] + bv;
          if (LAYER2) v += sdn[rt * 16 + quad * 4 + r] * rv;
          v = fmaxf(v, 0.f);
          outh[(size_t)row * FDIM + col] = (_Float16)v;
          s += v; q += v * v;
        }
      }
    }
    s += __shfl_xor(s, 16); q += __shfl_xor(q, 16);
    s += __shfl_xor(s, 32); q += __shfl_xor(q, 32);
    if (quad == 0) {
      atomicAdd(&ssum[col], s);
      atomicAdd(&ssq[col], q);
    }
  }
}

// ---------------- BN coeffs ----------------

__global__ void coeffs1_kernel(const float* __restrict__ sum, const float* __restrict__ sq,
                               const float* __restrict__ gamma, const float* __restrict__ beta,
                               const float* __restrict__ W2, float* __restrict__ a,
                               float* __restrict__ r2, int N) {
  __shared__ float cc[FDIM];
  int t = threadIdx.x;  // 128
  float invn = 1.f / (float)N;
  float mean = sum[t] * invn;
  float var = sq[t] * invn - mean * mean;
  float rs = rsqrtf(var + 1e-5f);
  float av = gamma[t] * rs;
  a[t] = av;
  cc[t] = beta[t] - mean * av;
  __syncthreads();
  float acc = 0.f;
  for (int k = 0; k < FDIM; k++) acc += cc[k] * W2[k * FDIM + t];
  r2[t] = acc;
}

__global__ void coeffs_kernel(const float* __restrict__ sum, const float* __restrict__ sq,
                              const float* __restrict__ gamma, const float* __restrict__ beta,
                              float* __restrict__ a, float* __restrict__ c, int N) {
  int t = threadIdx.x;
  if (t < FDIM) {
    float invn = 1.f / (float)N;
    float mean = sum[t] * invn;
    float var = sq[t] * invn - mean * mean;
    float rs = rsqrtf(var + 1e-5f);
    float av = gamma[t] * rs;
    a[t] = av;
    c[t] = beta[t] - mean * av;
  }
}

// BN2: read fp16 h2, write fp32 out
__global__ void apply_h_kernel(const uint2* __restrict__ h4, const float* __restrict__ a,
                               const float* __restrict__ c, float4* __restrict__ out, int n4) {
  int i = blockIdx.x * blockDim.x + threadIdx.x;
  if (i < n4) {
    uint2 u = h4[i];
    float2 v0 = up2(u.x), v1 = up2(u.y);
    int c4 = i & 31;
    float4 av = ((const float4*)a)[c4];
    float4 cv = ((const float4*)c)[c4];
    float4 o;
    o.x = av.x * v0.x + cv.x;
    o.y = av.y * v0.y + cv.y;
    o.z = av.z * v1.x + cv.z;
    o.w = av.w * v1.y + cv.w;
    out[i] = o;
  }
}

// ---------------- launch ----------------

extern "C" void kernel_launch(void* const* d_in, const int* in_sizes, int n_in,
                              void* d_out, int out_size, void* d_ws, size_t ws_size,
                              hipStream_t stream) {
  const float* x   = (const float*)d_in[0];
  const int*   ei  = (const int*)d_in[1];
  const float* W1  = (const float*)d_in[2];
  const float* b1  = (const float*)d_in[3];
  const float* W2  = (const float*)d_in[4];
  const float* b2  = (const float*)d_in[5];
  const float* g1  = (const float*)d_in[6];
  const float* be1 = (const float*)d_in[7];
  const float* g2  = (const float*)d_in[8];
  const float* be2 = (const float*)d_in[9];
  float* out = (float*)d_out;

  const int N = in_sizes[0] / FDIM;
  const int E = in_sizes[1] / 2;
  const int* src = ei;
  const int* dst = ei + E;

  auto align256 = [](char*& q) { q = (char*)(((uintptr_t)q + 255) & ~(uintptr_t)255); };

  char* p = (char*)d_ws;
  int* deg = (int*)p;        p += (size_t)N * 4;
  float* stats = (float*)p;  p += 1280 * 4;   // s1 q1 s2 q2 a1 r2 a2 c2 (+pad)
  align256(p);
  int* row_start = (int*)p;  p += (size_t)N * 4; align256(p);
  int* fill_pos = (int*)p;   p += (size_t)N * 4; align256(p);
  int* csums = (int*)p;      p += 256 * 4;
  int* coffs = (int*)p;      p += 256 * 4; align256(p);
  int* ssrc = (int*)p;       p += (size_t)E * 4; align256(p);
  _Float16* xh  = (_Float16*)p; p += (size_t)N * FDIM * 2; align256(p);
  _Float16* h1  = (_Float16*)p; p += (size_t)N * FDIM * 2; align256(p);
  _Float16* h2  = (_Float16*)p; p += (size_t)N * FDIM * 2; align256(p);
  _Float16* Wf1 = (_Float16*)p; p += FDIM * FDIM * 2;
  _Float16* Wf2 = (_Float16*)p; p += FDIM * FDIM * 2;

  float* s1 = stats + 0,   *q1 = stats + 128;
  float* s2 = stats + 256, *q2 = stats + 384;
  float* a1 = stats + 512, *r2 = stats + 640;
  float* a2 = stats + 768, *c2 = stats + 896;

  const int nchunk = (N + 1023) / 1024;
  const int ntiles = (N + 63) / 64;
  const int step = (N + NGRP - 1) / NGRP;

  // CSR build + conversions
  int zn = N + 1280;  // deg + stats region (contiguous)
  zero_kernel<<<(zn + 255) / 256, 256, 0, stream>>>(deg, zn);
  hist_part_kernel<<<NGRP * 128, 256, 0, stream>>>(dst, deg, E, step);
  cvt_f2h_kernel<<<(N * 32 + 255) / 256, 256, 0, stream>>>(x, xh, N * 32);
  prepw2_kernel<<<128, 256, 0, stream>>>(W1, Wf1, W2, Wf2);
  scan1_kernel<<<nchunk, 256, 0, stream>>>(deg, csums, N);
  scan2_kernel<<<1, 256, 0, stream>>>(csums, coffs, nchunk);
  scan3_kernel<<<nchunk, 256, 0, stream>>>(deg, coffs, row_start, fill_pos, N);
  place_part_kernel<<<NGRP * 128, 256, 0, stream>>>(src, dst, fill_pos, ssrc, E, step);

  // layer 1 (agg + GEMM + stats fused)
  layer_kernel<false><<<ntiles, 256, 0, stream>>>((const unsigned*)xh, row_start, deg, ssrc,
                                                  nullptr, Wf1, b1, nullptr, h1, s1, q1, N);
  coeffs1_kernel<<<1, 128, 0, stream>>>(s1, q1, g1, be1, W2, a1, r2, N);

  // layer 2: agg scales by a1; c1-term enters epilogue as (deg+1)*r2
  layer_kernel<true><<<ntiles, 256, 0, stream>>>((const unsigned*)h1, row_start, deg, ssrc,
                                                 a1, Wf2, b2, r2, h2, s2, q2, N);
  coeffs_kernel<<<1, 128, 0, stream>>>(s2, q2, g2, be2, a2, c2, N);

  // BN2: fp16 h2 -> fp32 out
  int n4 = N * 32;
  apply_h_kernel<<<(n4 + 255) / 256, 256, 0, stream>>>((const uint2*)h2, a2, c2,
                                                       (float4*)out, n4);
}